// Round 1
// baseline (362.435 us; speedup 1.0000x reference)
//
#include <hip/hip_runtime.h>
#include <math.h>

// Shapes: B=32, C=128, O=128, K=3, L=4096, W=1, PAD=1, DIL=1
// ws layout (floats):
//   Wr    [384*128]          transposed w_reg: Wr[(k*128+c)*128 + o]
//   idx0  [32*3*4096] (int)  clamped iy0
//   idx1  [32*3*4096] (int)  clamped iy0+1
//   wA    [32*3*4096]        mask*sx*wy0*valid0
//   wB    [32*3*4096]        mask*sx*wy1*valid1

#define NBKL (32*3*4096)

// ---------- kernel 0: transpose w_reg (O,C,K) -> Wr[(k*128+c)*128+o] ----------
__global__ __launch_bounds__(256) void k_transpose(const float* __restrict__ w_reg,
                                                   float* __restrict__ Wr) {
    int t = blockIdx.x * 256 + threadIdx.x;
    if (t >= 384 * 128) return;
    int o = t & 127;
    int rest = t >> 7;        // k*128 + c
    int c = rest & 127;
    int k = rest >> 7;
    Wr[t] = w_reg[(o * 128 + c) * 3 + k];
}

// ---------- kernel 1: offset/mask conv + gather-parameter precompute ----------
__global__ __launch_bounds__(256) void k_prep(const float* __restrict__ x,
                                              const float* __restrict__ w_off,
                                              const float* __restrict__ b_off,
                                              const float* __restrict__ w_mod,
                                              const float* __restrict__ b_mod,
                                              int* __restrict__ idx0,
                                              int* __restrict__ idx1,
                                              float* __restrict__ wA,
                                              float* __restrict__ wB) {
    __shared__ float ws[128 * 27];   // [c][ch*3+tap], ch 0..5 = w_off, 6..8 = w_mod
    int t = threadIdx.x;
    int b = blockIdx.y;
    int i = blockIdx.x * 256 + t;

    for (int idx = t; idx < 128 * 27; idx += 256) {
        int c = idx / 27, r = idx - c * 27;
        int ch = r / 3, tap = r - ch * 3;
        ws[idx] = (ch < 6) ? w_off[(ch * 128 + c) * 3 + tap]
                           : w_mod[((ch - 6) * 128 + c) * 3 + tap];
    }
    __syncthreads();

    float acc[9];
#pragma unroll
    for (int ch = 0; ch < 9; ++ch) acc[ch] = 0.f;

    const float* xr = x + (size_t)b * (128 * 4096);
    for (int c = 0; c < 128; ++c) {
        const float* row = xr + c * 4096;
        float xm1 = (i > 0)    ? row[i - 1] : 0.f;
        float x0  = row[i];
        float xp1 = (i < 4095) ? row[i + 1] : 0.f;
        const float* w = &ws[c * 27];
#pragma unroll
        for (int ch = 0; ch < 9; ++ch) {
            acc[ch] += xm1 * w[ch * 3 + 0] + x0 * w[ch * 3 + 1] + xp1 * w[ch * 3 + 2];
        }
    }

#pragma unroll
    for (int k = 0; k < 3; ++k) {
        float offy = acc[2 * k]     + b_off[2 * k];
        float offx = acc[2 * k + 1] + b_off[2 * k + 1];
        offy = fminf(fmaxf(offy, -1024.f), 1024.f);
        offx = fminf(fmaxf(offx, -1024.f), 1024.f);
        float am = acc[6 + k] + b_mod[k];
        float m  = 2.f / (1.f + expf(-am));

        float py = (float)(i - 1 + k) + offy;
        float px = offx;
        float y0 = floorf(py);
        int   iy0 = (int)y0;
        float wy1 = py - y0, wy0 = 1.f - wy1;
        float x0f = floorf(px);
        int   ix0 = (int)x0f;
        float wx1 = px - x0f, wx0 = 1.f - wx1;

        // only ix==0 is a valid x-sample (w==1)
        float sx = (ix0 == 0) ? wx0 : ((ix0 == -1) ? wx1 : 0.f);
        float scal = m * sx;

        float wAv = (iy0 >= 0 && iy0 < 4096)  ? scal * wy0 : 0.f;
        float wBv = (iy0 >= -1 && iy0 < 4095) ? scal * wy1 : 0.f;

        int j = (b * 3 + k) * 4096 + i;
        idx0[j] = min(max(iy0, 0), 4095);
        idx1[j] = min(max(iy0 + 1, 0), 4095);
        wA[j] = wAv;
        wB[j] = wBv;
    }
}

// ---------- kernel 2: gather -> G (LDS) -> [32x384]@[384x128] fp32 GEMM ----------
#define GSTRIDE 36   // padded row stride (words) for G[kc][i], 4-aligned, bank-spread
__global__ __launch_bounds__(256) void k_main(const float* __restrict__ x,
                                              const float* __restrict__ Wr,
                                              const int* __restrict__ idx0,
                                              const int* __restrict__ idx1,
                                              const float* __restrict__ wA,
                                              const float* __restrict__ wB,
                                              float* __restrict__ out) {
    __shared__ float G[384 * GSTRIDE];       // G[(k*128+c)][i_loc], 55.3 KB
    __shared__ int   s_i0[96], s_i1[96];
    __shared__ float s_wA[96], s_wB[96];

    int t = threadIdx.x;
    int b = blockIdx.y;
    int i0 = blockIdx.x * 32;

    if (t < 96) {                             // j = i_loc*3 + k
        int i_loc = t / 3, k = t - i_loc * 3;
        int j = (b * 3 + k) * 4096 + i0 + i_loc;
        s_i0[t] = idx0[j];
        s_i1[t] = idx1[j];
        s_wA[t] = wA[j];
        s_wB[t] = wB[j];
    }
    __syncthreads();

    // Phase 1: build G. thread -> (c, j); consecutive lanes share c, walk j
    const float* xb = x + (size_t)b * (128 * 4096);
    for (int it = t; it < 128 * 96; it += 256) {
        int c = it / 96, j = it - c * 96;
        int i_loc = j / 3, k = j - i_loc * 3;
        const float* row = xb + c * 4096;
        float v = s_wA[j] * row[s_i0[j]] + s_wB[j] * row[s_i1[j]];
        G[(k * 128 + c) * GSTRIDE + i_loc] = v;
    }
    __syncthreads();

    // Phase 2: out[b, og*4+qo, i0+io*4+qi] = sum_kc G[kc][i]*Wr[kc][o]
    int io = t & 7;        // 8 groups of 4 i  -> 32 i
    int og = t >> 3;       // 32 groups of 4 o -> 128 o
    float acc[4][4];
#pragma unroll
    for (int a = 0; a < 4; ++a)
#pragma unroll
        for (int q = 0; q < 4; ++q) acc[a][q] = 0.f;

    const float4* WrV = (const float4*)Wr;
#pragma unroll 4
    for (int kc = 0; kc < 384; ++kc) {
        float4 w = WrV[kc * 32 + og];
        float4 g = *(const float4*)&G[kc * GSTRIDE + io * 4];
        float gv[4] = {g.x, g.y, g.z, g.w};
        float wv[4] = {w.x, w.y, w.z, w.w};
#pragma unroll
        for (int a = 0; a < 4; ++a)
#pragma unroll
            for (int q = 0; q < 4; ++q) acc[a][q] += gv[a] * wv[q];
    }

#pragma unroll
    for (int qo = 0; qo < 4; ++qo) {
        float4 v = make_float4(acc[0][qo], acc[1][qo], acc[2][qo], acc[3][qo]);
        *(float4*)&out[((size_t)(b * 128 + og * 4 + qo)) * 4096 + i0 + io * 4] = v;
    }
}

extern "C" void kernel_launch(void* const* d_in, const int* in_sizes, int n_in,
                              void* d_out, int out_size, void* d_ws, size_t ws_size,
                              hipStream_t stream) {
    const float* x     = (const float*)d_in[0];
    const float* w_off = (const float*)d_in[1];
    const float* b_off = (const float*)d_in[2];
    const float* w_mod = (const float*)d_in[3];
    const float* b_mod = (const float*)d_in[4];
    const float* w_reg = (const float*)d_in[5];
    float* out = (float*)d_out;

    float* ws_f = (float*)d_ws;
    float* Wr   = ws_f;                       // 49152 floats
    int*   idx0 = (int*)(ws_f + 49152);
    int*   idx1 = idx0 + NBKL;
    float* wA   = (float*)(idx1 + NBKL);
    float* wB   = wA + NBKL;

    k_transpose<<<192, 256, 0, stream>>>(w_reg, Wr);
    k_prep<<<dim3(16, 32), 256, 0, stream>>>(x, w_off, b_off, w_mod, b_mod,
                                             idx0, idx1, wA, wB);
    k_main<<<dim3(128, 32), 256, 0, stream>>>(x, Wr, idx0, idx1, wA, wB, out);
}

// Round 2
// 186.434 us; speedup vs baseline: 1.9440x; 1.9440x over previous
//
#include <hip/hip_runtime.h>
#include <hip/hip_bf16.h>
#include <math.h>

// Shapes: B=32, C=128, O=128, K=3, L=4096, W=1, PAD=1, DIL=1
// Strategy: bf16 MFMA GEMM out[b,o,i] = sum_kc Wr[kc,o] * G[b,kc,i]
//   kc = k*128 + c (K-dim = 384), M = o (128), N = i (4096 per b)
// All MFMA operands stored in fragment-ready order so the GEMM needs no LDS.
//
// ws layout (bytes):
//   WrA   @ 0        : 8 m-frags x 12 k-steps x 64 lanes x 16B = 98304 B (pad->131072)
//   iyraw @ 131072   : int[32*3*4096]   raw iy0
//   wA    @ 1703936  : float[32*3*4096] mask*sx*wy0*valid0
//   wB    @ 3276800  : float[32*3*4096] mask*sx*wy1*valid1
//   G     @ 4849664  : 32 b x 256 i-frags x 12 k-steps x 64 lanes x 16B = 100663296 B

#define NBKL (32*3*4096)

typedef __attribute__((ext_vector_type(8))) short bf16x8;
typedef __attribute__((ext_vector_type(4))) float f32x4;

static __device__ inline unsigned short f2bf(float f) {
    __hip_bfloat16 h = __float2bfloat16(f);
    union { __hip_bfloat16 b; unsigned short u; } cv;
    cv.b = h;
    return cv.u;
}

// ---------- kernel 0: w_reg (O,C,K) -> A-fragment-ready bf16 WrA ----------
// A-frag (m,s), lane l, elem e:  A[o = m*16+(l&15)][kc = s*32+(l>>4)*8+e]
// stored at bf16 index t = ((m*12+s)*64+l)*8+e
__global__ __launch_bounds__(256) void k_wra(const float* __restrict__ w_reg,
                                             unsigned short* __restrict__ WrA) {
    int t = blockIdx.x * 256 + threadIdx.x;
    if (t >= 8 * 12 * 64 * 8) return;
    int e  = t & 7;
    int l  = (t >> 3) & 63;
    int ms = t >> 9;              // m*12 + s
    int m  = ms / 12;
    int s  = ms - m * 12;
    int o  = m * 16 + (l & 15);
    int kc = s * 32 + ((l >> 4) & 3) * 8 + e;
    int tap = kc >> 7;            // k index 0..2
    int c   = kc & 127;
    WrA[t] = f2bf(w_reg[(o * 128 + c) * 3 + tap]);
}

// ---------- kernel 1: offset/mask conv + gather-parameter precompute ----------
__global__ __launch_bounds__(256) void k_prep(const float* __restrict__ x,
                                              const float* __restrict__ w_off,
                                              const float* __restrict__ b_off,
                                              const float* __restrict__ w_mod,
                                              const float* __restrict__ b_mod,
                                              int* __restrict__ iyraw,
                                              float* __restrict__ wA,
                                              float* __restrict__ wB) {
    __shared__ float ws[128 * 27];   // [c][ch*3+tap], ch 0..5 = w_off, 6..8 = w_mod
    int t = threadIdx.x;
    int b = blockIdx.y;
    int i = blockIdx.x * 256 + t;

    for (int idx = t; idx < 128 * 27; idx += 256) {
        int c = idx / 27, r = idx - c * 27;
        int ch = r / 3, tap = r - ch * 3;
        ws[idx] = (ch < 6) ? w_off[(ch * 128 + c) * 3 + tap]
                           : w_mod[((ch - 6) * 128 + c) * 3 + tap];
    }
    __syncthreads();

    float acc[9];
#pragma unroll
    for (int ch = 0; ch < 9; ++ch) acc[ch] = 0.f;

    const float* xr = x + (size_t)b * (128 * 4096);
    for (int c = 0; c < 128; ++c) {
        const float* row = xr + c * 4096;
        float xm1 = (i > 0)    ? row[i - 1] : 0.f;
        float x0  = row[i];
        float xp1 = (i < 4095) ? row[i + 1] : 0.f;
        const float* w = &ws[c * 27];
#pragma unroll
        for (int ch = 0; ch < 9; ++ch) {
            acc[ch] += xm1 * w[ch * 3 + 0] + x0 * w[ch * 3 + 1] + xp1 * w[ch * 3 + 2];
        }
    }

#pragma unroll
    for (int k = 0; k < 3; ++k) {
        float offy = acc[2 * k]     + b_off[2 * k];
        float offx = acc[2 * k + 1] + b_off[2 * k + 1];
        offy = fminf(fmaxf(offy, -1024.f), 1024.f);
        offx = fminf(fmaxf(offx, -1024.f), 1024.f);
        float am = acc[6 + k] + b_mod[k];
        float m  = 2.f / (1.f + expf(-am));

        float py = (float)(i - 1 + k) + offy;
        float px = offx;
        float y0 = floorf(py);
        int   iy0 = (int)y0;
        float wy1 = py - y0, wy0 = 1.f - wy1;
        float x0f = floorf(px);
        int   ix0 = (int)x0f;
        float wx1 = px - x0f, wx0 = 1.f - wx1;

        // only ix==0 is a valid x-sample (w==1)
        float sx = (ix0 == 0) ? wx0 : ((ix0 == -1) ? wx1 : 0.f);
        float scal = m * sx;

        float wAv = (iy0 >= 0 && iy0 < 4096)  ? scal * wy0 : 0.f;
        float wBv = (iy0 >= -1 && iy0 < 4095) ? scal * wy1 : 0.f;

        int j = (b * 3 + k) * 4096 + i;
        iyraw[j] = iy0;
        wA[j] = wAv;
        wB[j] = wBv;
    }
}

// ---------- kernel 2: gather -> G in B-fragment-ready bf16 order ----------
// B-frag (i-frag f, k-step s), lane l = (i&15)+16*q, elem e: kc = s*32+q*8+e
// chunk index (uint4 units) = b*196608 + (f*12+s)*64 + l
__global__ __launch_bounds__(256) void k_gather(const float* __restrict__ x,
                                                const int* __restrict__ iyraw,
                                                const float* __restrict__ wA,
                                                const float* __restrict__ wB,
                                                uint4* __restrict__ G) {
    int t = threadIdx.x;
    int b = blockIdx.y;
    int i = blockIdx.x * 256 + t;
    const float* xb = x + (size_t)b * 524288;
    uint4* Gb = G + (size_t)b * 196608;
    int base_chunk = (i >> 4) * (12 * 64) + (i & 15);

#pragma unroll
    for (int k = 0; k < 3; ++k) {
        int j = (b * 3 + k) * 4096 + i;
        int iy = iyraw[j];
        float a  = wA[j];
        float bw = wB[j];
        int i0 = min(max(iy, 0), 4095);
        int i1 = min(max(iy + 1, 0), 4095);

        for (int c8 = 0; c8 < 16; ++c8) {
            float v[8];
#pragma unroll
            for (int e = 0; e < 8; ++e) {
                const float* row = xb + (size_t)(c8 * 8 + e) * 4096;
                v[e] = a * row[i0] + bw * row[i1];
            }
            uint4 p;
            p.x = (unsigned)f2bf(v[0]) | ((unsigned)f2bf(v[1]) << 16);
            p.y = (unsigned)f2bf(v[2]) | ((unsigned)f2bf(v[3]) << 16);
            p.z = (unsigned)f2bf(v[4]) | ((unsigned)f2bf(v[5]) << 16);
            p.w = (unsigned)f2bf(v[6]) | ((unsigned)f2bf(v[7]) << 16);
            int s = k * 4 + (c8 >> 2);
            int q = c8 & 3;
            Gb[base_chunk + s * 64 + q * 16] = p;
        }
    }
}

// ---------- kernel 3: zero-LDS MFMA GEMM ----------
// block: b = blockIdx.y, 128-i tile = blockIdx.x; 4 waves; wave w owns i-frags
// {ib*8+2w, ib*8+2w+1}, all 8 o-frags, K=384 in 12 steps of 32.
__global__ __launch_bounds__(256) void k_gemm(const bf16x8* __restrict__ WrA,
                                              const bf16x8* __restrict__ G,
                                              float* __restrict__ out) {
    int t = threadIdx.x;
    int l = t & 63;
    int w = t >> 6;
    int b  = blockIdx.y;
    int ib = blockIdx.x;
    const bf16x8* Gb = G + (size_t)b * 196608;
    int f0 = ib * 8 + 2 * w;

    f32x4 acc[8][2];
#pragma unroll
    for (int m = 0; m < 8; ++m) {
        acc[m][0] = (f32x4){0.f, 0.f, 0.f, 0.f};
        acc[m][1] = (f32x4){0.f, 0.f, 0.f, 0.f};
    }

#pragma unroll 2
    for (int s = 0; s < 12; ++s) {
        bf16x8 B0 = Gb[(size_t)(f0 * 12 + s) * 64 + l];
        bf16x8 B1 = Gb[(size_t)((f0 + 1) * 12 + s) * 64 + l];
#pragma unroll
        for (int m = 0; m < 8; ++m) {
            bf16x8 A = WrA[(size_t)(m * 12 + s) * 64 + l];
            acc[m][0] = __builtin_amdgcn_mfma_f32_16x16x32_bf16(A, B0, acc[m][0], 0, 0, 0);
            acc[m][1] = __builtin_amdgcn_mfma_f32_16x16x32_bf16(A, B1, acc[m][1], 0, 0, 0);
        }
    }

    // C layout (verified m89): col = lane&15, row = (lane>>4)*4 + reg
    int col = l & 15;
    int r0  = (l >> 4) * 4;
#pragma unroll
    for (int m = 0; m < 8; ++m) {
#pragma unroll
        for (int j = 0; j < 2; ++j) {
            int ig = ib * 128 + (2 * w + j) * 16 + col;
#pragma unroll
            for (int r = 0; r < 4; ++r) {
                int o = m * 16 + r0 + r;
                out[((size_t)(b * 128 + o)) * 4096 + ig] = acc[m][j][r];
            }
        }
    }
}

extern "C" void kernel_launch(void* const* d_in, const int* in_sizes, int n_in,
                              void* d_out, int out_size, void* d_ws, size_t ws_size,
                              hipStream_t stream) {
    const float* x     = (const float*)d_in[0];
    const float* w_off = (const float*)d_in[1];
    const float* b_off = (const float*)d_in[2];
    const float* w_mod = (const float*)d_in[3];
    const float* b_mod = (const float*)d_in[4];
    const float* w_reg = (const float*)d_in[5];
    float* out = (float*)d_out;

    char* ws = (char*)d_ws;
    unsigned short* WrA = (unsigned short*)(ws);
    int*   iyraw = (int*)  (ws + 131072);
    float* wA    = (float*)(ws + 1703936);
    float* wB    = (float*)(ws + 3276800);
    uint4* G     = (uint4*)(ws + 4849664);

    k_wra<<<192, 256, 0, stream>>>(w_reg, WrA);
    k_prep<<<dim3(16, 32), 256, 0, stream>>>(x, w_off, b_off, w_mod, b_mod,
                                             iyraw, wA, wB);
    k_gather<<<dim3(16, 32), 256, 0, stream>>>(x, iyraw, wA, wB, G);
    k_gemm<<<dim3(32, 32), 256, 0, stream>>>((const bf16x8*)WrA, (const bf16x8*)G, out);
}

// Round 3
// 121.176 us; speedup vs baseline: 2.9910x; 1.5385x over previous
//
#include <hip/hip_runtime.h>
#include <hip/hip_bf16.h>
#include <math.h>

// Shapes: B=32, C=128, O=128, K=3, L=4096, W=1, PAD=1, DIL=1
// out[b,o,i] = sum_kc Wr[kc,o] * G[b,kc,i],  kc = k*128+c (K=384)
// G[b,kc,i] = wa_eff[b,k,i] * x[b,c,addr] + wb_eff[b,k,i] * x[b,c,addr+1]
// Fused: G gathered straight into MFMA B-fragments (no G tensor).
//
// ws layout (bytes):
//   WrA   @ 0        : 8 m-frags x 12 k-steps x 64 lanes x 16B = 98304 (pad->131072)
//   addr2 @ 131072   : int[32*3*4096]   clamp(iy0,0,4094)
//   wae   @ 1703936  : float[32*3*4096] effective weight for x[addr]
//   wbe   @ 3276800  : float[32*3*4096] effective weight for x[addr+1]

#define NBKL (32*3*4096)

typedef __attribute__((ext_vector_type(8))) short bf16x8;
typedef __attribute__((ext_vector_type(4))) float f32x4;
typedef float f32x2u __attribute__((ext_vector_type(2), aligned(4)));

static __device__ inline unsigned short f2bf(float f) {
    __hip_bfloat16 h = __float2bfloat16(f);
    union { __hip_bfloat16 b; unsigned short u; } cv;
    cv.b = h;
    return cv.u;
}

// ---------- kernel 0: w_reg (O,C,K) -> A-fragment-ready bf16 WrA ----------
// A-frag (m,s), lane l, elem e:  A[o = m*16+(l&15)][kc = s*32+(l>>4)*8+e]
__global__ __launch_bounds__(256) void k_wra(const float* __restrict__ w_reg,
                                             unsigned short* __restrict__ WrA) {
    int t = blockIdx.x * 256 + threadIdx.x;
    if (t >= 8 * 12 * 64 * 8) return;
    int e  = t & 7;
    int l  = (t >> 3) & 63;
    int ms = t >> 9;              // m*12 + s
    int m  = ms / 12;
    int s  = ms - m * 12;
    int o  = m * 16 + (l & 15);
    int kc = s * 32 + ((l >> 4) & 3) * 8 + e;
    int tap = kc >> 7;            // k index 0..2
    int c   = kc & 127;
    WrA[t] = f2bf(w_reg[(o * 128 + c) * 3 + tap]);
}

// ---------- kernel 1: offset/mask conv, wave-split over channels ----------
// grid (64, 32): 64-i tiles. Wave w sums c in [32w,32w+32); LDS reduce.
__global__ __launch_bounds__(256) void k_prep(const float* __restrict__ x,
                                              const float* __restrict__ w_off,
                                              const float* __restrict__ b_off,
                                              const float* __restrict__ w_mod,
                                              const float* __restrict__ b_mod,
                                              int* __restrict__ addr2,
                                              float* __restrict__ wae,
                                              float* __restrict__ wbe) {
    __shared__ float ws[128 * 27];      // [c][ch*3+tap], ch 0..5 off, 6..8 mod
    __shared__ float red[3 * 64 * 9];   // partials from waves 1..3
    int t = threadIdx.x;
    int lane = t & 63;
    int wv = t >> 6;
    int b = blockIdx.y;
    int i = blockIdx.x * 64 + lane;

    for (int idx = t; idx < 128 * 27; idx += 256) {
        int c = idx / 27, r = idx - c * 27;
        int ch = r / 3, tap = r - ch * 3;
        ws[idx] = (ch < 6) ? w_off[(ch * 128 + c) * 3 + tap]
                           : w_mod[((ch - 6) * 128 + c) * 3 + tap];
    }
    __syncthreads();

    float acc[9];
#pragma unroll
    for (int ch = 0; ch < 9; ++ch) acc[ch] = 0.f;

    const float* xr = x + (size_t)b * 524288 + (size_t)(wv * 32) * 4096;
    const float* wbase = &ws[(wv * 32) * 27];
#pragma unroll 2
    for (int c = 0; c < 32; ++c) {
        const float* row = xr + (size_t)c * 4096;
        float xm1 = (i > 0)    ? row[i - 1] : 0.f;
        float x0  = row[i];
        float xp1 = (i < 4095) ? row[i + 1] : 0.f;
        const float* w = wbase + c * 27;
#pragma unroll
        for (int ch = 0; ch < 9; ++ch) {
            acc[ch] += xm1 * w[ch * 3 + 0] + x0 * w[ch * 3 + 1] + xp1 * w[ch * 3 + 2];
        }
    }

    if (wv > 0) {
        float* r = &red[((wv - 1) * 64 + lane) * 9];
#pragma unroll
        for (int ch = 0; ch < 9; ++ch) r[ch] = acc[ch];
    }
    __syncthreads();
    if (wv != 0) return;

#pragma unroll
    for (int ch = 0; ch < 9; ++ch) {
        acc[ch] += red[(0 * 64 + lane) * 9 + ch]
                 + red[(1 * 64 + lane) * 9 + ch]
                 + red[(2 * 64 + lane) * 9 + ch];
    }

#pragma unroll
    for (int k = 0; k < 3; ++k) {
        float offy = acc[2 * k]     + b_off[2 * k];
        float offx = acc[2 * k + 1] + b_off[2 * k + 1];
        offy = fminf(fmaxf(offy, -1024.f), 1024.f);
        offx = fminf(fmaxf(offx, -1024.f), 1024.f);
        float am = acc[6 + k] + b_mod[k];
        float m  = 2.f / (1.f + expf(-am));

        float py = (float)(i - 1 + k) + offy;
        float y0 = floorf(py);
        int   iy0 = (int)y0;
        float wy1 = py - y0, wy0 = 1.f - wy1;
        float x0f = floorf(offx);
        int   ix0 = (int)x0f;
        float wx1 = offx - x0f, wx0 = 1.f - wx1;

        float sx = (ix0 == 0) ? wx0 : ((ix0 == -1) ? wx1 : 0.f);
        float scal = m * sx;

        float wAv = (iy0 >= 0 && iy0 < 4096)  ? scal * wy0 : 0.f;
        float wBv = (iy0 >= -1 && iy0 < 4095) ? scal * wy1 : 0.f;

        int addr = min(max(iy0, 0), 4094);
        bool eq = (iy0 == addr);
        float wa = eq ? wAv : (iy0 == -1   ? wBv : 0.f);
        float wb = eq ? wBv : (iy0 == 4095 ? wAv : 0.f);

        int j = (b * 3 + k) * 4096 + i;
        addr2[j] = addr;
        wae[j] = wa;
        wbe[j] = wb;
    }
}

// ---------- kernel 2: fused gather + MFMA GEMM ----------
// grid (32, 32): 128-i tiles. Wave w owns i-frags {ib*8+2w, ib*8+2w+1},
// all 8 o-frags. B-frags gathered from x directly into registers.
__global__ __launch_bounds__(256) void k_fused(const bf16x8* __restrict__ WrA,
                                               const float* __restrict__ x,
                                               const int* __restrict__ addr2,
                                               const float* __restrict__ wae,
                                               const float* __restrict__ wbe,
                                               float* __restrict__ out) {
    int t = threadIdx.x;
    int l = t & 63;
    int w = t >> 6;
    int b = blockIdx.y;
    int ib = blockIdx.x;
    int q = l >> 4;
    int il = l & 15;
    int f0 = ib * 8 + 2 * w;
    int i0 = f0 * 16 + il;
    const float* xb = x + (size_t)b * 524288;

    f32x4 acc[8][2];
#pragma unroll
    for (int m = 0; m < 8; ++m) {
        acc[m][0] = (f32x4){0.f, 0.f, 0.f, 0.f};
        acc[m][1] = (f32x4){0.f, 0.f, 0.f, 0.f};
    }

    for (int k = 0; k < 3; ++k) {
        int j0 = (b * 3 + k) * 4096 + i0;
        int a0 = addr2[j0];
        float wa0 = wae[j0], wb0 = wbe[j0];
        int j1 = j0 + 16;
        int a1 = addr2[j1];
        float wa1 = wae[j1], wb1 = wbe[j1];

#pragma unroll
        for (int ss = 0; ss < 4; ++ss) {
            int s = k * 4 + ss;
            int cb = ss * 32 + q * 8;
            float v0[8], v1[8];
#pragma unroll
            for (int e = 0; e < 8; ++e) {
                const float* row = xb + (size_t)(cb + e) * 4096;
                f32x2u p0 = *(const f32x2u*)(row + a0);
                f32x2u p1 = *(const f32x2u*)(row + a1);
                v0[e] = wa0 * p0.x + wb0 * p0.y;
                v1[e] = wa1 * p1.x + wb1 * p1.y;
            }
            bf16x8 B0, B1;
#pragma unroll
            for (int e = 0; e < 8; ++e) {
                B0[e] = (short)f2bf(v0[e]);
                B1[e] = (short)f2bf(v1[e]);
            }
#pragma unroll
            for (int m = 0; m < 8; ++m) {
                bf16x8 A = WrA[(size_t)(m * 12 + s) * 64 + l];
                acc[m][0] = __builtin_amdgcn_mfma_f32_16x16x32_bf16(A, B0, acc[m][0], 0, 0, 0);
                acc[m][1] = __builtin_amdgcn_mfma_f32_16x16x32_bf16(A, B1, acc[m][1], 0, 0, 0);
            }
        }
    }

    // C layout: col = lane&15, row = (lane>>4)*4 + reg
    int col = il;
    int r0  = q * 4;
#pragma unroll
    for (int m = 0; m < 8; ++m) {
#pragma unroll
        for (int j = 0; j < 2; ++j) {
            int ig = ib * 128 + (2 * w + j) * 16 + col;
#pragma unroll
            for (int r = 0; r < 4; ++r) {
                int o = m * 16 + r0 + r;
                out[((size_t)(b * 128 + o)) * 4096 + ig] = acc[m][j][r];
            }
        }
    }
}

extern "C" void kernel_launch(void* const* d_in, const int* in_sizes, int n_in,
                              void* d_out, int out_size, void* d_ws, size_t ws_size,
                              hipStream_t stream) {
    const float* x     = (const float*)d_in[0];
    const float* w_off = (const float*)d_in[1];
    const float* b_off = (const float*)d_in[2];
    const float* w_mod = (const float*)d_in[3];
    const float* b_mod = (const float*)d_in[4];
    const float* w_reg = (const float*)d_in[5];
    float* out = (float*)d_out;

    char* ws = (char*)d_ws;
    unsigned short* WrA = (unsigned short*)(ws);
    int*   addr2 = (int*)  (ws + 131072);
    float* wae   = (float*)(ws + 1703936);
    float* wbe   = (float*)(ws + 3276800);

    k_wra<<<192, 256, 0, stream>>>(w_reg, WrA);
    k_prep<<<dim3(64, 32), 256, 0, stream>>>(x, w_off, b_off, w_mod, b_mod,
                                             addr2, wae, wbe);
    k_fused<<<dim3(32, 32), 256, 0, stream>>>((const bf16x8*)WrA, x,
                                              addr2, wae, wbe, out);
}

// Round 4
// 88.765 us; speedup vs baseline: 4.0831x; 1.3651x over previous
//
#include <hip/hip_runtime.h>
#include <hip/hip_bf16.h>
#include <math.h>

// Shapes: B=32, C=128, O=128, K=3, L=4096, W=1, PAD=1, DIL=1
// out[b,o,i] = sum_kc Wr[kc,o] * G[b,kc,i],  kc = k*128+c (K=384)
// G[b,kc,i] = wae[b,k,i]*x[b,c,addr] + wbe[b,k,i]*x[b,c,addr+1]
//
// ws layout (bytes):
//   WrA @ 0       : bf16 A-frags, 8 m x 12 s x 64 lanes x 16B = 98304
//   wT  @ 98304   : float[128*32] transposed conv weights, wT[c*32+ch*3+tap]
//   addr2 @ 131072: int[32*3*4096]
//   wae @ 1703936 : float[32*3*4096]
//   wbe @ 3276800 : float[32*3*4096]

#define NBKL (32*3*4096)

typedef __attribute__((ext_vector_type(8))) short bf16x8;
typedef __attribute__((ext_vector_type(4))) float f32x4;
typedef float f32x2u __attribute__((ext_vector_type(2), aligned(4)));

static __device__ inline unsigned short f2bf(float f) {
    __hip_bfloat16 h = __float2bfloat16(f);
    union { __hip_bfloat16 b; unsigned short u; } cv;
    cv.b = h;
    return cv.u;
}

// ---------- kernel 0: pack WrA (A-frags) + wT (transposed conv weights) ----------
// A-frag (m,s), lane l, elem e:  A[o = m*16+(l&15)][kc = s*32+(l>>4)*8+e]
__global__ __launch_bounds__(256) void k_wra(const float* __restrict__ w_reg,
                                             const float* __restrict__ w_off,
                                             const float* __restrict__ w_mod,
                                             unsigned short* __restrict__ WrA,
                                             float* __restrict__ wT) {
    int t = blockIdx.x * 256 + threadIdx.x;
    if (t < 8 * 12 * 64 * 8) {
        int e  = t & 7;
        int l  = (t >> 3) & 63;
        int ms = t >> 9;              // m*12 + s
        int m  = ms / 12;
        int s  = ms - m * 12;
        int o  = m * 16 + (l & 15);
        int kc = s * 32 + ((l >> 4) & 3) * 8 + e;
        int tap = kc >> 7;
        int c   = kc & 127;
        WrA[t] = f2bf(w_reg[(o * 128 + c) * 3 + tap]);
    } else if (t < 8 * 12 * 64 * 8 + 128 * 27) {
        int u = t - 8 * 12 * 64 * 8;
        int c = u / 27, r = u - c * 27;
        int ch = r / 3, tap = r - ch * 3;
        wT[c * 32 + r] = (ch < 6) ? w_off[(ch * 128 + c) * 3 + tap]
                                  : w_mod[((ch - 6) * 128 + c) * 3 + tap];
    }
}

// ---------- kernel 1: offset/mask conv ----------
// grid (32, 32): 128-i tiles. Wave wv sums c in [32wv, 32wv+32); lane owns 2 i.
__global__ __launch_bounds__(256, 4) void k_prep(const float* __restrict__ x,
                                                 const float* __restrict__ wT,
                                                 const float* __restrict__ b_off,
                                                 const float* __restrict__ b_mod,
                                                 int* __restrict__ addr2,
                                                 float* __restrict__ wae,
                                                 float* __restrict__ wbe) {
    __shared__ float red[3 * 64 * 18];
    int t = threadIdx.x;
    int lane = t & 63;
    int wv = t >> 6;
    int b = blockIdx.y;
    int i = blockIdx.x * 128 + lane * 2;          // lane covers i, i+1

    int c0 = __builtin_amdgcn_readfirstlane(wv) * 32;

    float acc[18];
#pragma unroll
    for (int z = 0; z < 18; ++z) acc[z] = 0.f;

    const float* xr = x + (size_t)b * 524288 + (size_t)c0 * 4096;
    const float* wbase = wT + c0 * 32;
#pragma unroll 2
    for (int c = 0; c < 32; ++c) {
        const float* row = xr + (size_t)c * 4096;
        f32x2u xc = *(const f32x2u*)(row + i);
        float xm1v = row[max(i - 1, 0)];
        float xp2v = row[min(i + 2, 4095)];
        float xm1 = (i > 0)    ? xm1v : 0.f;
        float xp2 = (i + 2 <= 4095) ? xp2v : 0.f;
        const float* wrow = wbase + c * 32;       // wave-uniform -> s_load
#pragma unroll
        for (int ch = 0; ch < 9; ++ch) {
            float w0 = wrow[ch * 3 + 0];
            float w1 = wrow[ch * 3 + 1];
            float w2 = wrow[ch * 3 + 2];
            acc[ch * 2 + 0] += xm1  * w0 + xc.x * w1 + xc.y * w2;
            acc[ch * 2 + 1] += xc.x * w0 + xc.y * w1 + xp2  * w2;
        }
    }

    if (wv > 0) {
        float* r = &red[((wv - 1) * 64 + lane) * 18];
#pragma unroll
        for (int z = 0; z < 18; ++z) r[z] = acc[z];
    }
    __syncthreads();
    if (wv != 0) return;

#pragma unroll
    for (int z = 0; z < 18; ++z) {
        acc[z] += red[(0 * 64 + lane) * 18 + z]
                + red[(1 * 64 + lane) * 18 + z]
                + red[(2 * 64 + lane) * 18 + z];
    }

#pragma unroll
    for (int k = 0; k < 3; ++k) {
        int   av[2];
        float wav[2], wbv[2];
#pragma unroll
        for (int ii = 0; ii < 2; ++ii) {
            float offy = acc[(2 * k) * 2 + ii]     + b_off[2 * k];
            float offx = acc[(2 * k + 1) * 2 + ii] + b_off[2 * k + 1];
            offy = fminf(fmaxf(offy, -1024.f), 1024.f);
            offx = fminf(fmaxf(offx, -1024.f), 1024.f);
            float am = acc[(6 + k) * 2 + ii] + b_mod[k];
            float m  = 2.f / (1.f + expf(-am));

            float py = (float)(i + ii - 1 + k) + offy;
            float y0 = floorf(py);
            int   iy0 = (int)y0;
            float wy1 = py - y0, wy0 = 1.f - wy1;
            float x0f = floorf(offx);
            int   ix0 = (int)x0f;
            float wx1 = offx - x0f, wx0 = 1.f - wx1;

            float sx = (ix0 == 0) ? wx0 : ((ix0 == -1) ? wx1 : 0.f);
            float scal = m * sx;

            float wAv = (iy0 >= 0 && iy0 < 4096)  ? scal * wy0 : 0.f;
            float wBv = (iy0 >= -1 && iy0 < 4095) ? scal * wy1 : 0.f;

            int addr = min(max(iy0, 0), 4094);
            bool eq = (iy0 == addr);
            wav[ii] = eq ? wAv : (iy0 == -1   ? wBv : 0.f);
            wbv[ii] = eq ? wBv : (iy0 == 4095 ? wAv : 0.f);
            av[ii] = addr;
        }
        int j = (b * 3 + k) * 4096 + i;
        *(int2*)(addr2 + j)  = make_int2(av[0], av[1]);
        *(f32x2u*)(wae + j)  = (f32x2u){wav[0], wav[1]};
        *(f32x2u*)(wbe + j)  = (f32x2u){wbv[0], wbv[1]};
    }
}

// ---------- kernel 2: fused gather + MFMA GEMM, WrA half in LDS ----------
// grid (32 i-tiles, 2 o-halves, 32 b). Block 256 = 4 waves.
// Block tile: 128 i x 64 o. Wave w: i-frags {2w,2w+1}, m-frags 0..3 of the half.
__global__ __launch_bounds__(256, 3) void k_fused(const unsigned short* __restrict__ WrA,
                                                  const float* __restrict__ x,
                                                  const int* __restrict__ addr2,
                                                  const float* __restrict__ wae,
                                                  const float* __restrict__ wbe,
                                                  float* __restrict__ out) {
    __shared__ char lds[49152];                    // 4 m x 12 s x 64 x 16B
    int t = threadIdx.x;
    int l = t & 63;
    int w = t >> 6;
    int b  = blockIdx.z;
    int ob = blockIdx.y;
    int ib = blockIdx.x;
    int q = l >> 4;
    int il = l & 15;
    int f0 = ib * 8 + 2 * w;
    int i0 = f0 * 16 + il;
    const float* xb = x + (size_t)b * 524288;

    // stage this o-half's A-fragments into LDS (48 KB, linear copy)
    {
        const uint4* src = (const uint4*)(WrA + (size_t)ob * 24576);  // 49152 B
        uint4* dst = (uint4*)lds;
#pragma unroll
        for (int it = 0; it < 12; ++it) {
            dst[it * 256 + t] = src[it * 256 + t];
        }
    }
    __syncthreads();
    const bf16x8* ldsA = (const bf16x8*)lds;

    f32x4 acc[4][2];
#pragma unroll
    for (int m = 0; m < 4; ++m) {
        acc[m][0] = (f32x4){0.f, 0.f, 0.f, 0.f};
        acc[m][1] = (f32x4){0.f, 0.f, 0.f, 0.f};
    }

    for (int k = 0; k < 3; ++k) {
        int j0 = (b * 3 + k) * 4096 + i0;
        int a0 = addr2[j0];
        float wa0 = wae[j0], wb0 = wbe[j0];
        int j1 = j0 + 16;
        int a1 = addr2[j1];
        float wa1 = wae[j1], wb1 = wbe[j1];

#pragma unroll
        for (int ss = 0; ss < 4; ++ss) {
            int s = k * 4 + ss;
            int cb = ss * 32 + q * 8;
            float v0[8], v1[8];
#pragma unroll
            for (int e = 0; e < 8; ++e) {
                const float* row = xb + (size_t)(cb + e) * 4096;
                f32x2u p0 = *(const f32x2u*)(row + a0);
                f32x2u p1 = *(const f32x2u*)(row + a1);
                v0[e] = wa0 * p0.x + wb0 * p0.y;
                v1[e] = wa1 * p1.x + wb1 * p1.y;
            }
            bf16x8 B0, B1;
#pragma unroll
            for (int e = 0; e < 8; ++e) {
                B0[e] = (short)f2bf(v0[e]);
                B1[e] = (short)f2bf(v1[e]);
            }
#pragma unroll
            for (int m = 0; m < 4; ++m) {
                bf16x8 A = ldsA[(m * 12 + s) * 64 + l];
                acc[m][0] = __builtin_amdgcn_mfma_f32_16x16x32_bf16(A, B0, acc[m][0], 0, 0, 0);
                acc[m][1] = __builtin_amdgcn_mfma_f32_16x16x32_bf16(A, B1, acc[m][1], 0, 0, 0);
            }
        }
    }

    // C layout: col = lane&15, row = (lane>>4)*4 + reg
    int col = il;
    int r0  = q * 4;
#pragma unroll
    for (int m = 0; m < 4; ++m) {
#pragma unroll
        for (int j = 0; j < 2; ++j) {
            int ig = ib * 128 + (2 * w + j) * 16 + col;
#pragma unroll
            for (int r = 0; r < 4; ++r) {
                int o = ob * 64 + m * 16 + r0 + r;
                out[((size_t)(b * 128 + o)) * 4096 + ig] = acc[m][j][r];
            }
        }
    }
}

extern "C" void kernel_launch(void* const* d_in, const int* in_sizes, int n_in,
                              void* d_out, int out_size, void* d_ws, size_t ws_size,
                              hipStream_t stream) {
    const float* x     = (const float*)d_in[0];
    const float* w_off = (const float*)d_in[1];
    const float* b_off = (const float*)d_in[2];
    const float* w_mod = (const float*)d_in[3];
    const float* b_mod = (const float*)d_in[4];
    const float* w_reg = (const float*)d_in[5];
    float* out = (float*)d_out;

    char* ws = (char*)d_ws;
    unsigned short* WrA = (unsigned short*)(ws);
    float* wT    = (float*)(ws + 98304);
    int*   addr2 = (int*)  (ws + 131072);
    float* wae   = (float*)(ws + 1703936);
    float* wbe   = (float*)(ws + 3276800);

    k_wra<<<206, 256, 0, stream>>>(w_reg, w_off, w_mod, WrA, wT);
    k_prep<<<dim3(32, 32), 256, 0, stream>>>(x, wT, b_off, b_mod,
                                             addr2, wae, wbe);
    k_fused<<<dim3(32, 2, 32), 256, 0, stream>>>(WrA, x, addr2, wae, wbe, out);
}

// Round 5
// 82.975 us; speedup vs baseline: 4.3680x; 1.0698x over previous
//
#include <hip/hip_runtime.h>
#include <hip/hip_bf16.h>
#include <math.h>

// Shapes: B=32, C=128, O=128, K=3, L=4096, W=1, PAD=1, DIL=1
// out[b,o,i] = sum_kc Wr[kc,o] * G[b,kc,i],  kc = k*128+c (K=384)
// G[b,kc,i] = wae[b,k,i]*x[b,c,addr] + wbe[b,k,i]*x[b,c,addr+1]
//
// k_fused: per block (128-i tile, one b, all 128 o):
//   stage x window [32c x 160i] fp32 in LDS per channel-block (coalesced),
//   interp via ds_read2 (both corners, one instr), MFMA with A-frags from L2.
//   Wave-uniform fallback to global gathers when any addr exits the window.
//
// ws layout (bytes):
//   WrA @ 0       : bf16 A-frags, 8 m x 12 s x 64 lanes x 16B = 98304
//   wT  @ 98304   : float[128*32] transposed conv weights, wT[c*32+ch*3+tap]
//   addr2 @ 131072: int[32*3*4096]
//   wae @ 1703936 : float[32*3*4096]
//   wbe @ 3276800 : float[32*3*4096]

typedef __attribute__((ext_vector_type(8))) short bf16x8;
typedef __attribute__((ext_vector_type(4))) float f32x4;
typedef float f32x2u __attribute__((ext_vector_type(2), aligned(4)));

#define WIN 160
#define WPAD 161   // dword stride; (8*161)%32=8 -> q-groups bank-offset, <=2-way

static __device__ inline unsigned short f2bf(float f) {
    __hip_bfloat16 h = __float2bfloat16(f);
    union { __hip_bfloat16 b; unsigned short u; } cv;
    cv.b = h;
    return cv.u;
}

// ---------- kernel 0: pack WrA (A-frags) + wT (transposed conv weights) ----------
// A-frag (m,s), lane l, elem e:  A[o = m*16+(l&15)][kc = s*32+(l>>4)*8+e]
__global__ __launch_bounds__(256) void k_wra(const float* __restrict__ w_reg,
                                             const float* __restrict__ w_off,
                                             const float* __restrict__ w_mod,
                                             unsigned short* __restrict__ WrA,
                                             float* __restrict__ wT) {
    int t = blockIdx.x * 256 + threadIdx.x;
    if (t < 8 * 12 * 64 * 8) {
        int e  = t & 7;
        int l  = (t >> 3) & 63;
        int ms = t >> 9;              // m*12 + s
        int m  = ms / 12;
        int s  = ms - m * 12;
        int o  = m * 16 + (l & 15);
        int kc = s * 32 + ((l >> 4) & 3) * 8 + e;
        int tap = kc >> 7;
        int c   = kc & 127;
        WrA[t] = f2bf(w_reg[(o * 128 + c) * 3 + tap]);
    } else if (t < 8 * 12 * 64 * 8 + 128 * 27) {
        int u = t - 8 * 12 * 64 * 8;
        int c = u / 27, r = u - c * 27;
        int ch = r / 3, tap = r - ch * 3;
        wT[c * 32 + r] = (ch < 6) ? w_off[(ch * 128 + c) * 3 + tap]
                                  : w_mod[((ch - 6) * 128 + c) * 3 + tap];
    }
}

// ---------- kernel 1: offset/mask conv ----------
// grid (64, 32): 64-i tiles, 1 i per lane. Wave wv sums c in [32wv, 32wv+32).
__global__ __launch_bounds__(256) void k_prep(const float* __restrict__ x,
                                              const float* __restrict__ wT,
                                              const float* __restrict__ b_off,
                                              const float* __restrict__ b_mod,
                                              int* __restrict__ addr2,
                                              float* __restrict__ wae,
                                              float* __restrict__ wbe) {
    __shared__ float red[3 * 64 * 9];
    int t = threadIdx.x;
    int lane = t & 63;
    int wv = t >> 6;
    int b = blockIdx.y;
    int i = blockIdx.x * 64 + lane;

    int c0 = __builtin_amdgcn_readfirstlane(wv) * 32;

    float acc[9];
#pragma unroll
    for (int z = 0; z < 9; ++z) acc[z] = 0.f;

    const float* xr = x + (size_t)b * 524288 + (size_t)c0 * 4096;
    const float* wbase = wT + c0 * 32;
#pragma unroll 2
    for (int c = 0; c < 32; ++c) {
        const float* row = xr + (size_t)c * 4096;
        float xm1v = row[max(i - 1, 0)];
        float x0   = row[i];
        float xp1v = row[min(i + 1, 4095)];
        float xm1 = (i > 0)    ? xm1v : 0.f;
        float xp1 = (i < 4095) ? xp1v : 0.f;
        const float* wrow = wbase + c * 32;       // wave-uniform -> s_load
#pragma unroll
        for (int ch = 0; ch < 9; ++ch) {
            acc[ch] += xm1 * wrow[ch * 3 + 0] + x0 * wrow[ch * 3 + 1]
                     + xp1 * wrow[ch * 3 + 2];
        }
    }

    if (wv > 0) {
        float* r = &red[((wv - 1) * 64 + lane) * 9];
#pragma unroll
        for (int z = 0; z < 9; ++z) r[z] = acc[z];
    }
    __syncthreads();
    if (wv != 0) return;

#pragma unroll
    for (int z = 0; z < 9; ++z) {
        acc[z] += red[(0 * 64 + lane) * 9 + z]
                + red[(1 * 64 + lane) * 9 + z]
                + red[(2 * 64 + lane) * 9 + z];
    }

#pragma unroll
    for (int k = 0; k < 3; ++k) {
        float offy = acc[2 * k]     + b_off[2 * k];
        float offx = acc[2 * k + 1] + b_off[2 * k + 1];
        offy = fminf(fmaxf(offy, -1024.f), 1024.f);
        offx = fminf(fmaxf(offx, -1024.f), 1024.f);
        float am = acc[6 + k] + b_mod[k];
        float m  = 2.f / (1.f + expf(-am));

        float py = (float)(i - 1 + k) + offy;
        float y0 = floorf(py);
        int   iy0 = (int)y0;
        float wy1 = py - y0, wy0 = 1.f - wy1;
        float x0f = floorf(offx);
        int   ix0 = (int)x0f;
        float wx1 = offx - x0f, wx0 = 1.f - wx1;

        float sx = (ix0 == 0) ? wx0 : ((ix0 == -1) ? wx1 : 0.f);
        float scal = m * sx;

        float wAv = (iy0 >= 0 && iy0 < 4096)  ? scal * wy0 : 0.f;
        float wBv = (iy0 >= -1 && iy0 < 4095) ? scal * wy1 : 0.f;

        int addr = min(max(iy0, 0), 4094);
        bool eq = (iy0 == addr);
        float wa = eq ? wAv : (iy0 == -1   ? wBv : 0.f);
        float wb = eq ? wBv : (iy0 == 4095 ? wAv : 0.f);

        int j = (b * 3 + k) * 4096 + i;
        addr2[j] = addr;
        wae[j] = wa;
        wbe[j] = wb;
    }
}

// ---------- kernel 2: fused gather + MFMA GEMM, LDS x-window ----------
// grid (32 i-tiles, 32 b), 256 threads = 4 waves. Block: 128 i x 128 o.
// Wave w: i-frags {2w, 2w+1}, all 8 m-frags.
__global__ __launch_bounds__(256) void k_fused(const unsigned short* __restrict__ WrA,
                                               const float* __restrict__ x,
                                               const int* __restrict__ addr2,
                                               const float* __restrict__ wae,
                                               const float* __restrict__ wbe,
                                               float* __restrict__ out) {
    __shared__ float win[32 * WPAD];               // 20.6 KB
    int t = threadIdx.x;
    int l = t & 63;
    int w = t >> 6;
    int b  = blockIdx.y;
    int ib = blockIdx.x;
    int q = l >> 4;
    int il = l & 15;
    int f0 = ib * 8 + 2 * w;
    int i0 = f0 * 16 + il;
    int i0t = ib * 128;
    int wsod = i0t - 16;
    if (wsod > 4096 - WIN) wsod = 4096 - WIN;
    if (wsod < 0) wsod = 0;
    const float* xb = x + (size_t)b * 524288;
    const bf16x8* Ag = (const bf16x8*)WrA;

    // hoist per-(k, i-frag) gather params + wave-uniform in-window flags
    int   a_[3][2];
    float wa_[3][2], wb_[3][2];
    bool  okw[3][2];
#pragma unroll
    for (int k = 0; k < 3; ++k) {
#pragma unroll
        for (int jj = 0; jj < 2; ++jj) {
            int j = (b * 3 + k) * 4096 + i0 + jj * 16;
            int a = addr2[j];
            a_[k][jj]  = a;
            wa_[k][jj] = wae[j];
            wb_[k][jj] = wbe[j];
            okw[k][jj] = (bool)__all(a >= wsod && a <= wsod + WIN - 2);
        }
    }

    f32x4 acc[8][2];
#pragma unroll
    for (int m = 0; m < 8; ++m) {
        acc[m][0] = (f32x4){0.f, 0.f, 0.f, 0.f};
        acc[m][1] = (f32x4){0.f, 0.f, 0.f, 0.f};
    }

    for (int cc = 0; cc < 4; ++cc) {
        int cb = cc * 32;
        __syncthreads();                            // window free to overwrite
        // stage window: 32 rows x 160 fp32, coalesced dwordx4
#pragma unroll
        for (int it = 0; it < 5; ++it) {
            int idx = it * 256 + t;                 // 0..1279 x4-chunks
            int r  = idx / 40;
            int cp = idx - r * 40;
            float4 v = *(const float4*)(xb + (size_t)(cb + r) * 4096 + wsod + cp * 4);
            float* dst = &win[r * WPAD + cp * 4];
            dst[0] = v.x; dst[1] = v.y; dst[2] = v.z; dst[3] = v.w;
        }
        __syncthreads();

#pragma unroll
        for (int k = 0; k < 3; ++k) {
            int s = k * 4 + cc;
            bf16x8 Bf[2];
#pragma unroll
            for (int jj = 0; jj < 2; ++jj) {
                float v[8];
                float wa = wa_[k][jj], wb = wb_[k][jj];
                if (okw[k][jj]) {
                    int p = a_[k][jj] - wsod;
#pragma unroll
                    for (int e = 0; e < 8; ++e) {
                        const float* base = &win[(q * 8 + e) * WPAD + p];
                        v[e] = wa * base[0] + wb * base[1];   // ds_read2_b32
                    }
                } else {
                    int a = a_[k][jj];
#pragma unroll
                    for (int e = 0; e < 8; ++e) {
                        const float* row = xb + (size_t)(cb + q * 8 + e) * 4096;
                        f32x2u p2 = *(const f32x2u*)(row + a);
                        v[e] = wa * p2.x + wb * p2.y;
                    }
                }
                bf16x8 Bv;
#pragma unroll
                for (int e = 0; e < 8; ++e) Bv[e] = (short)f2bf(v[e]);
                Bf[jj] = Bv;
            }
#pragma unroll
            for (int m = 0; m < 8; ++m) {
                bf16x8 A = Ag[(m * 12 + s) * 64 + l];
                acc[m][0] = __builtin_amdgcn_mfma_f32_16x16x32_bf16(A, Bf[0], acc[m][0], 0, 0, 0);
                acc[m][1] = __builtin_amdgcn_mfma_f32_16x16x32_bf16(A, Bf[1], acc[m][1], 0, 0, 0);
            }
        }
    }

    // C layout: col = lane&15, row = (lane>>4)*4 + reg
    int col = il;
    int r0  = q * 4;
#pragma unroll
    for (int m = 0; m < 8; ++m) {
#pragma unroll
        for (int jj = 0; jj < 2; ++jj) {
            int ig = i0t + (2 * w + jj) * 16 + col;
#pragma unroll
            for (int r = 0; r < 4; ++r) {
                int o = m * 16 + r0 + r;
                out[((size_t)(b * 128 + o)) * 4096 + ig] = acc[m][jj][r];
            }
        }
    }
}

extern "C" void kernel_launch(void* const* d_in, const int* in_sizes, int n_in,
                              void* d_out, int out_size, void* d_ws, size_t ws_size,
                              hipStream_t stream) {
    const float* x     = (const float*)d_in[0];
    const float* w_off = (const float*)d_in[1];
    const float* b_off = (const float*)d_in[2];
    const float* w_mod = (const float*)d_in[3];
    const float* b_mod = (const float*)d_in[4];
    const float* w_reg = (const float*)d_in[5];
    float* out = (float*)d_out;

    char* ws = (char*)d_ws;
    unsigned short* WrA = (unsigned short*)(ws);
    float* wT    = (float*)(ws + 98304);
    int*   addr2 = (int*)  (ws + 131072);
    float* wae   = (float*)(ws + 1703936);
    float* wbe   = (float*)(ws + 3276800);

    k_wra<<<206, 256, 0, stream>>>(w_reg, w_off, w_mod, WrA, wT);
    k_prep<<<dim3(64, 32), 256, 0, stream>>>(x, wT, b_off, b_mod,
                                             addr2, wae, wbe);
    k_fused<<<dim3(32, 32), 256, 0, stream>>>(WrA, x, addr2, wae, wbe, out);
}